// Round 9
// baseline (344.593 us; speedup 1.0000x reference)
//
#include <hip/hip_runtime.h>

#define DFEAT 128
#define NGRP 8
#define SSLOT 8          // slab slots per (grp, node) segment
#define OVCAP 32768      // overflow list capacity (expected ~100 used)
#define FILL_BLOCKS 2048 // co-resident fill grid (8 blocks/CU x 256 CU)
#define EPT 8            // max edges per fill thread

typedef __attribute__((ext_vector_type(8))) short short8v;   // 8 bf16
typedef __attribute__((ext_vector_type(4))) float f32x4;     // MFMA C/D
typedef __attribute__((ext_vector_type(4))) unsigned short ushort4v;

__device__ __forceinline__ unsigned short f2bf(float f) {
    union { float f; unsigned u; } cv; cv.f = f;
    unsigned u = cv.u + 0x7fffu + ((cv.u >> 16) & 1u);   // RNE
    return (unsigned short)(u >> 16);
}
__device__ __forceinline__ float bf2f(unsigned short h) {
    union { unsigned u; float f; } cv; cv.u = ((unsigned)h) << 16; return cv.f;
}
__device__ __forceinline__ int load_idx(const void* eiv, int is64, size_t i) {
    return is64 ? (int)((const long long*)eiv)[i] : ((const int*)eiv)[i];
}

// ---------------------------------------------------------------------------
// Fused prep: edge-dtype detect + W->bf16^T + x->bf16 + zero counts/ovcnt.
// ---------------------------------------------------------------------------
__global__ __launch_bounds__(256) void convert_all_kernel(
        const float* __restrict__ W1, const float* __restrict__ W2,
        unsigned short* __restrict__ w1bf, unsigned short* __restrict__ w2bf,
        const float* __restrict__ x, unsigned short* __restrict__ xb, int total4,
        const int* __restrict__ ei, int* __restrict__ flag,
        int* __restrict__ counts, int* __restrict__ ovcnt, int M, int xbBlocks) {
    int b = blockIdx.x;
    if (b == 0 && threadIdx.x == 0) {
        int orsum = 0;
#pragma unroll
        for (int i = 0; i < 128; ++i) orsum |= ei[2 * i + 1];
        flag[0] = (orsum == 0) ? 1 : 0;
    }
    if (b < 128) {
        const float* W = (b < 64) ? W1 : W2;
        unsigned short* o = (b < 64) ? w1bf : w2bf;
        int idx = (b & 63) * 256 + threadIdx.x;   // idx = k*128+n
        int k = idx >> 7, n = idx & 127;
        o[n * 128 + k] = f2bf(W[idx]);
    } else if (b < 128 + xbBlocks) {
        int i = (b - 128) * 256 + threadIdx.x;
        if (i < total4) {
            float4 v = *(const float4*)&x[(size_t)i * 4];
            ushort4v o;
            o.x = f2bf(v.x); o.y = f2bf(v.y); o.z = f2bf(v.z); o.w = f2bf(v.w);
            *(ushort4v*)&xb[(size_t)i * 4] = o;
        }
    } else {
        int i = (b - 128 - xbBlocks) * 256 + threadIdx.x;  // int4 index
        int base = i * 4;
        if (base + 3 < M) {
            ((int4*)counts)[i] = make_int4(0, 0, 0, 0);
        } else {
            for (int j = base; j < M; ++j) counts[j] = 0;
        }
        if (i == 0) ovcnt[0] = 0;
    }
}

// ---------------------------------------------------------------------------
// Slab fill (R8-proven): dst-range sweeps for temporal write clustering.
// slab layout [grp][node][SSLOT], counts [grp][N], grp = blockIdx&7 ~ XCD.
// ---------------------------------------------------------------------------
__global__ __launch_bounds__(256) void fill_slab_kernel(
        const void* __restrict__ eiv, const int* __restrict__ flag,
        int* __restrict__ counts, int* __restrict__ ovcnt,
        int2* __restrict__ ov, int* __restrict__ slab, int E, int N, int nblk) {
    const int tid = blockIdx.x * 256 + threadIdx.x;
    const int stride = nblk * 256;
    const int grp = blockIdx.x & (NGRP - 1);
    const int is64 = flag[0];

    int sr[EPT], ds[EPT];
    int k = 0;
    for (int e = tid; e < E && k < EPT; e += stride) {
        sr[k] = load_idx(eiv, is64, (size_t)e);
        ds[k] = load_idx(eiv, is64, (size_t)E + e);
        ++k;
    }

    const int sz = (N + NGRP - 1) / NGRP;
    for (int s = 0; s < NGRP; ++s) {
        int lo = s * sz, hi = lo + sz;
#pragma unroll
        for (int i = 0; i < EPT; ++i) {
            if (i < k && ds[i] >= lo && ds[i] < hi) {
                int pos = atomicAdd(&counts[(size_t)grp * N + ds[i]], 1);
                if (pos < SSLOT)
                    slab[((size_t)grp * N + ds[i]) * SSLOT + pos] = sr[i];
                else {
                    int o = atomicAdd(ovcnt, 1);
                    if (o < OVCAP) ov[o] = make_int2(ds[i], sr[i]);
                }
            }
        }
    }
}

// ---------------------------------------------------------------------------
// FUSED agg + MLP. Block = 64 nodes, 256 threads.
// Phase A: each 32-lane group drains 8 nodes (slab -> LDS compaction ->
//   16 independent row gathers per batch), h = (1+eps)*x + sum -> hlds (bf16).
//   comp scratch aliased into wlds (W staging is after the barrier).
// Phase B: R4-proven MFMA MLP out = relu(h@W1+b1)@W2+b2 from hlds.
// LDS 52KB -> 3 blocks/CU; 16-wide drain keeps ~384 gathers in flight/CU.
// ---------------------------------------------------------------------------
__global__ __launch_bounds__(256) void agg_mlp_kernel(
        const unsigned short* __restrict__ xb,
        const int* __restrict__ counts,       // [NGRP][N]
        const int* __restrict__ slab,         // [NGRP][N][SSLOT]
        const int* __restrict__ ovcnt, const int2* __restrict__ ov,
        const float* __restrict__ epsp,
        const unsigned short* __restrict__ w1bf,
        const unsigned short* __restrict__ w2bf,
        const float* __restrict__ b1, const float* __restrict__ b2,
        float* __restrict__ out, int N) {
    __shared__ unsigned short hlds[64 * 136];
    __shared__ unsigned short wlds[128 * 136];
    int(*comp)[64] = (int(*)[64])wlds;        // phase-A scratch, 2KB, aliased

    const int tid  = threadIdx.x;
    const int node0 = blockIdx.x * 64;
    const int lane = tid & 31;
    const int grpq = tid >> 5;                // 0..7
    const int base = tid & 32;                // ballot shift for 32-lane group
    const float epsv = 1.0f + epsp[0];

    // ---- Phase A: aggregate 8 nodes per group into hlds ----
    const int g = lane >> 2, s0 = (lane & 3) * 2;
    const int c = lane * 4;
    const int ovn = min(ovcnt[0], OVCAP);
    const unsigned lt = (lane == 0) ? 0u : (~0u >> (32 - lane));

    for (int j = 0; j < 8; ++j) {
        const int m = grpq * 8 + j;
        const int node = node0 + m;
        if (node < N) {
            int2 sl = *(const int2*)&slab[((size_t)g * N + node) * SSLOT + s0];
            int cnt = min(counts[(size_t)g * N + node], SSLOT);
            bool v0 = s0 < cnt, v1 = (s0 + 1) < cnt;
            unsigned m0 = (unsigned)(__ballot(v0) >> base);
            unsigned m1 = (unsigned)(__ballot(v1) >> base);
            int t0 = __popc(m0);
            int total = t0 + __popc(m1);
            if (v0) comp[grpq][__popc(m0 & lt)] = sl.x;
            if (v1) comp[grpq][t0 + __popc(m1 & lt)] = sl.y;
            // wave-synchronous LDS: same wave writes then reads its slice

            ushort4v own = *(const ushort4v*)&xb[(size_t)node * DFEAT + c];
            float ax = epsv * bf2f(own.x), ay = epsv * bf2f(own.y);
            float az = epsv * bf2f(own.z), aw = epsv * bf2f(own.w);

            for (int i = 0; i < total; i += 16) {
                int4 q0 = *(const int4*)&comp[grpq][i];
                int4 q1 = *(const int4*)&comp[grpq][i + 4];
                int4 q2 = *(const int4*)&comp[grpq][i + 8];
                int4 q3 = *(const int4*)&comp[grpq][i + 12];
                int rem = total - i;
                int sj[16];
                sj[0]  = q0.x;
                sj[1]  = (rem > 1)  ? q0.y : q0.x;
                sj[2]  = (rem > 2)  ? q0.z : q0.x;
                sj[3]  = (rem > 3)  ? q0.w : q0.x;
                sj[4]  = (rem > 4)  ? q1.x : q0.x;
                sj[5]  = (rem > 5)  ? q1.y : q0.x;
                sj[6]  = (rem > 6)  ? q1.z : q0.x;
                sj[7]  = (rem > 7)  ? q1.w : q0.x;
                sj[8]  = (rem > 8)  ? q2.x : q0.x;
                sj[9]  = (rem > 9)  ? q2.y : q0.x;
                sj[10] = (rem > 10) ? q2.z : q0.x;
                sj[11] = (rem > 11) ? q2.w : q0.x;
                sj[12] = (rem > 12) ? q3.x : q0.x;
                sj[13] = (rem > 13) ? q3.y : q0.x;
                sj[14] = (rem > 14) ? q3.z : q0.x;
                sj[15] = (rem > 15) ? q3.w : q0.x;
                ushort4v u[16];
#pragma unroll
                for (int q = 0; q < 16; ++q)
                    u[q] = *(const ushort4v*)&xb[(size_t)sj[q] * DFEAT + c];
#pragma unroll
                for (int q = 0; q < 16; ++q) {
                    if (rem > q) {
                        ax += bf2f(u[q].x); ay += bf2f(u[q].y);
                        az += bf2f(u[q].z); aw += bf2f(u[q].w);
                    }
                }
            }

            // overflow replay (tiny list, L2-resident)
            int trips = (ovn + 31) >> 5;
            for (int t = 0; t < trips; ++t) {
                int jj = t * 32 + lane;
                int2 e = (jj < ovn) ? ov[jj] : make_int2(-1, 0);
                unsigned long long b = __ballot(e.x == node);
                unsigned mm = (unsigned)(b >> base);
                while (mm) {
                    int l = __ffs(mm) - 1; mm &= mm - 1;
                    int s = __shfl(e.y, base + l, 64);
                    ushort4v u = *(const ushort4v*)&xb[(size_t)s * DFEAT + c];
                    ax += bf2f(u.x); ay += bf2f(u.y);
                    az += bf2f(u.z); aw += bf2f(u.w);
                }
            }

            ushort4v hv;
            hv.x = f2bf(ax); hv.y = f2bf(ay); hv.z = f2bf(az); hv.w = f2bf(aw);
            *(ushort4v*)&hlds[m * 136 + c] = hv;
        } else {
            ushort4v z = {0, 0, 0, 0};
            *(ushort4v*)&hlds[m * 136 + c] = z;
        }
    }
    __syncthreads();   // hlds complete; comp scratch dead -> stage W into wlds

    // ---- Phase B: MFMA MLP ----
    const int lane64 = tid & 63;
    const int w    = tid >> 6;
    const int l15  = lane64 & 15;
    const int quad = lane64 >> 4;

    for (int i = tid; i < 128 * 16; i += 256) {
        int n = i >> 4, k0 = (i & 15) * 8;
        *(short8v*)&wlds[n * 136 + k0] = *(const short8v*)&w1bf[n * 128 + k0];
    }
    __syncthreads();

    const unsigned short* ha = &hlds[(w * 16 + l15) * 136 + quad * 8];

    for (int layer = 0; layer < 2; ++layer) {
        if (layer == 1) {
            __syncthreads();
            for (int i = tid; i < 128 * 16; i += 256) {
                int n = i >> 4, k0 = (i & 15) * 8;
                *(short8v*)&wlds[n * 136 + k0] = *(const short8v*)&w2bf[n * 128 + k0];
            }
            __syncthreads();
        }

        f32x4 acc[8];
#pragma unroll
        for (int nt = 0; nt < 8; ++nt) acc[nt] = (f32x4){0.f, 0.f, 0.f, 0.f};

#pragma unroll
        for (int s = 0; s < 4; ++s) {
            short8v a = *(const short8v*)&ha[s * 32];
#pragma unroll
            for (int nt = 0; nt < 8; ++nt) {
                short8v bf = *(const short8v*)&wlds[(nt * 16 + l15) * 136 + quad * 8 + s * 32];
                acc[nt] = __builtin_amdgcn_mfma_f32_16x16x32_bf16(a, bf, acc[nt], 0, 0, 0);
            }
        }

        const float* bias = layer ? b2 : b1;
        if (layer == 0) {
            __syncthreads();   // all hlds reads done before overwrite
#pragma unroll
            for (int nt = 0; nt < 8; ++nt) {
                float bv = bias[nt * 16 + l15];
#pragma unroll
                for (int r = 0; r < 4; ++r) {
                    float v = fmaxf(acc[nt][r] + bv, 0.f);
                    hlds[(w * 16 + quad * 4 + r) * 136 + nt * 16 + l15] = f2bf(v);
                }
            }
        } else {
#pragma unroll
            for (int nt = 0; nt < 8; ++nt) {
                float bv = bias[nt * 16 + l15];
#pragma unroll
                for (int r = 0; r < 4; ++r) {
                    int node = node0 + w * 16 + quad * 4 + r;
                    if (node < N)
                        out[(size_t)node * DFEAT + nt * 16 + l15] = acc[nt][r] + bv;
                }
            }
        }
    }
}

// ===========================================================================
// Fallback (tiny ws): atomic scatter + fp32 vector MLP
// ===========================================================================
__global__ void detect_idx_kernel(const int* __restrict__ ei, int* __restrict__ flag) {
    if (threadIdx.x == 0 && blockIdx.x == 0) {
        int orsum = 0;
#pragma unroll
        for (int i = 0; i < 128; ++i) orsum |= ei[2 * i + 1];
        flag[0] = (orsum == 0) ? 1 : 0;
    }
}

__global__ __launch_bounds__(256) void scatter_kernel(
        const float* __restrict__ x, const void* __restrict__ eiv,
        const int* __restrict__ flag, float* __restrict__ agg, int E) {
    unsigned gid = blockIdx.x * 256u + threadIdx.x;
    unsigned e = gid >> 5;
    if (e >= (unsigned)E) return;
    int c = (gid & 31u) * 4;
    int is64 = flag[0];
    int src = load_idx(eiv, is64, (size_t)e);
    int dst = load_idx(eiv, is64, (size_t)E + e);
    float4 v = *(const float4*)&x[(size_t)src * DFEAT + c];
    float* p = &agg[(size_t)dst * DFEAT + c];
    unsafeAtomicAdd(p + 0, v.x);
    unsafeAtomicAdd(p + 1, v.y);
    unsafeAtomicAdd(p + 2, v.z);
    unsafeAtomicAdd(p + 3, v.w);
}

__global__ __launch_bounds__(256) void mlp_kernel(
        const float* __restrict__ xp,
        const float* __restrict__ W1, const float* __restrict__ b1,
        const float* __restrict__ W2, const float* __restrict__ b2,
        const float* __restrict__ epsp, float* __restrict__ out) {
    __shared__ float hs[32][DFEAT];
    __shared__ float Wc[64][DFEAT];

    const int tid = threadIdx.x;
    const int node0 = blockIdx.x * 32;
    const float epsv = 1.0f + epsp[0];

    for (int i = tid; i < 32 * (DFEAT / 4); i += 256) {
        int n = i >> 5;
        int c = (i & 31) * 4;
        size_t off = (size_t)(node0 + n) * DFEAT + c;
        float4 h = *(const float4*)&out[off];
        float4 xv = *(const float4*)&xp[off];
        h.x += epsv * xv.x; h.y += epsv * xv.y;
        h.z += epsv * xv.z; h.w += epsv * xv.w;
        *(float4*)&hs[n][c] = h;
    }

    const int og = (tid & 31) * 4;
    const int ng = (tid >> 5) * 4;

    for (int layer = 0; layer < 2; ++layer) {
        const float* W = layer ? W2 : W1;
        const float* b = layer ? b2 : b1;

        float acc[4][4];
#pragma unroll
        for (int j = 0; j < 4; ++j) {
            float bj = b[og + j];
#pragma unroll
            for (int i = 0; i < 4; ++i) acc[i][j] = bj;
        }

        for (int chunk = 0; chunk < 2; ++chunk) {
            __syncthreads();
            for (int i = tid; i < 64 * (DFEAT / 4); i += 256) {
                int r = i >> 5;
                int c = (i & 31) * 4;
                *(float4*)&Wc[r][c] =
                    *(const float4*)&W[(size_t)(chunk * 64 + r) * DFEAT + c];
            }
            __syncthreads();
            const int kb = chunk * 64;
            for (int k = 0; k < 64; k += 4) {
                float4 h4[4], w4[4];
#pragma unroll
                for (int i = 0; i < 4; ++i)
                    h4[i] = *(const float4*)&hs[ng + i][kb + k];
#pragma unroll
                for (int j = 0; j < 4; ++j)
                    w4[j] = *(const float4*)&Wc[k + j][og];
#pragma unroll
                for (int i = 0; i < 4; ++i) {
                    acc[i][0] += h4[i].x * w4[0].x + h4[i].y * w4[1].x
                               + h4[i].z * w4[2].x + h4[i].w * w4[3].x;
                    acc[i][1] += h4[i].x * w4[0].y + h4[i].y * w4[1].y
                               + h4[i].z * w4[2].y + h4[i].w * w4[3].y;
                    acc[i][2] += h4[i].x * w4[0].z + h4[i].y * w4[1].z
                               + h4[i].z * w4[2].z + h4[i].w * w4[3].z;
                    acc[i][3] += h4[i].x * w4[0].w + h4[i].y * w4[1].w
                               + h4[i].z * w4[2].w + h4[i].w * w4[3].w;
                }
            }
        }
        __syncthreads();

        if (layer == 0) {
#pragma unroll
            for (int i = 0; i < 4; ++i) {
                float4 r;
                r.x = fmaxf(acc[i][0], 0.0f);
                r.y = fmaxf(acc[i][1], 0.0f);
                r.z = fmaxf(acc[i][2], 0.0f);
                r.w = fmaxf(acc[i][3], 0.0f);
                *(float4*)&hs[ng + i][og] = r;
            }
        } else {
#pragma unroll
            for (int i = 0; i < 4; ++i) {
                float4 r;
                r.x = acc[i][0]; r.y = acc[i][1];
                r.z = acc[i][2]; r.w = acc[i][3];
                *(float4*)&out[(size_t)(node0 + ng + i) * DFEAT + og] = r;
            }
        }
    }
}

extern "C" void kernel_launch(void* const* d_in, const int* in_sizes, int n_in,
                              void* d_out, int out_size, void* d_ws, size_t ws_size,
                              hipStream_t stream) {
    const float* x   = (const float*)d_in[0];
    const void*  ei  = d_in[1];
    const float* W1  = (const float*)d_in[2];
    const float* b1  = (const float*)d_in[3];
    const float* W2  = (const float*)d_in[4];
    const float* b2  = (const float*)d_in[5];
    const float* eps = (const float*)d_in[6];
    float* out = (float*)d_out;

    const int N = in_sizes[0] / DFEAT;      // 100000
    const int E = in_sizes[1] / 2;          // 1600000
    const int M = NGRP * N;                 // 800000 segments
    const int total4 = N * (DFEAT / 4);     // 3.2M float4s in x

    // ---- T1 layout: [flag][wbf][xb][counts][ovcnt][ov][slab] ----
    char* p = (char*)d_ws;
    int* flag = (int*)p;                        p += 64;
    unsigned short* w1bf = (unsigned short*)p;  p += 128 * 128 * 2;
    unsigned short* w2bf = (unsigned short*)p;  p += 128 * 128 * 2;
    unsigned short* xb = (unsigned short*)p;    p += (size_t)N * DFEAT * 2;
    int* counts = (int*)p;                      p += (size_t)M * 4;
    int* ovcnt = (int*)p;                       p += 64;
    int2* ov = (int2*)p;                        p += (size_t)OVCAP * 8;
    int* slab = (int*)p;                        p += (size_t)M * SSLOT * 4;
    size_t need = (size_t)(p - (char*)d_ws);

    if (ws_size >= need) {
        int xbBlocks = (total4 + 255) / 256;
        int czBlocks = (M / 4 + 255) / 256;
        convert_all_kernel<<<128 + xbBlocks + czBlocks, 256, 0, stream>>>(
            W1, W2, w1bf, w2bf, x, xb, total4, (const int*)ei, flag,
            counts, ovcnt, M, xbBlocks);
        int nblk = FILL_BLOCKS;
        if ((size_t)E > (size_t)FILL_BLOCKS * 256 * EPT)
            nblk = (E + 256 * EPT - 1) / (256 * EPT);
        fill_slab_kernel<<<nblk, 256, 0, stream>>>(
            ei, flag, counts, ovcnt, ov, slab, E, N, nblk);
        agg_mlp_kernel<<<(N + 63) / 64, 256, 0, stream>>>(
            xb, counts, slab, ovcnt, ov, eps, w1bf, w2bf, b1, b2, out, N);
        return;
    }

    // ---- fallback: atomic scatter + fp32 MLP ----
    int* flag3 = (int*)d_ws;
    detect_idx_kernel<<<1, 64, 0, stream>>>((const int*)ei, flag3);
    hipMemsetAsync(d_out, 0, (size_t)out_size * sizeof(float), stream);
    unsigned total = (unsigned)E * 32u;
    scatter_kernel<<<(total + 255u) / 256u, 256, 0, stream>>>(x, ei, flag3, out, E);
    mlp_kernel<<<N / 32, 256, 0, stream>>>(x, W1, b1, W2, b2, eps, out);
}

// Round 10
// 295.205 us; speedup vs baseline: 1.1673x; 1.1673x over previous
//
#include <hip/hip_runtime.h>

#define DFEAT 128
#define NGRP 8
#define SSLOT 8          // slab slots per (grp, node) segment
#define OVCAP 32768      // overflow list capacity (expected ~100 used)
#define FILL_BLOCKS 2048 // co-resident fill grid (8 blocks/CU x 256 CU)
#define EPT 8            // max edges per fill thread

typedef __attribute__((ext_vector_type(8))) short short8v;   // 8 bf16
typedef __attribute__((ext_vector_type(4))) float f32x4;     // MFMA C/D
typedef __attribute__((ext_vector_type(4))) unsigned short ushort4v;

__device__ __forceinline__ unsigned short f2bf(float f) {
    union { float f; unsigned u; } cv; cv.f = f;
    unsigned u = cv.u + 0x7fffu + ((cv.u >> 16) & 1u);   // RNE
    return (unsigned short)(u >> 16);
}
__device__ __forceinline__ float bf2f(unsigned short h) {
    union { unsigned u; float f; } cv; cv.u = ((unsigned)h) << 16; return cv.f;
}
__device__ __forceinline__ int load_idx(const void* eiv, int is64, size_t i) {
    return is64 ? (int)((const long long*)eiv)[i] : ((const int*)eiv)[i];
}

// ---------------------------------------------------------------------------
// Fused prep: fill (blocks 0..nfill-1, launched first: latency-bound, overlaps
// the BW-bound converts) + W->bf16^T (next 128 blocks) + x->bf16 (rest).
// counts/ovcnt pre-zeroed by hipMemsetAsync. Each fill block self-detects the
// edge dtype (512B broadcast read) -- no cross-block dependency.
// ---------------------------------------------------------------------------
__global__ __launch_bounds__(256) void prep_kernel(
        const float* __restrict__ W1, const float* __restrict__ W2,
        unsigned short* __restrict__ w1bf, unsigned short* __restrict__ w2bf,
        const float* __restrict__ x, unsigned short* __restrict__ xb, int total4,
        const void* __restrict__ eiv,
        int* __restrict__ counts, int* __restrict__ ovcnt,
        int2* __restrict__ ov, int* __restrict__ slab,
        int E, int N, int nfill) {
    const int b = blockIdx.x;

    if (b < nfill) {
        // ---- fill part (R8-proven dst-range sweeps) ----
        const int* e32 = (const int*)eiv;
        int orsum = 0;
#pragma unroll
        for (int i = 0; i < 128; ++i) orsum |= e32[2 * i + 1];
        const int is64 = (orsum == 0);

        const int gtid = b * 256 + threadIdx.x;
        const int stride = nfill * 256;
        const int grp = b & (NGRP - 1);

        int sr[EPT], ds[EPT];
        int k = 0;
        for (int e = gtid; e < E && k < EPT; e += stride) {
            sr[k] = load_idx(eiv, is64, (size_t)e);
            ds[k] = load_idx(eiv, is64, (size_t)E + e);
            ++k;
        }

        const int sz = (N + NGRP - 1) / NGRP;
        for (int s = 0; s < NGRP; ++s) {
            int lo = s * sz, hi = lo + sz;
#pragma unroll
            for (int i = 0; i < EPT; ++i) {
                if (i < k && ds[i] >= lo && ds[i] < hi) {
                    int pos = atomicAdd(&counts[(size_t)grp * N + ds[i]], 1);
                    if (pos < SSLOT)
                        slab[((size_t)grp * N + ds[i]) * SSLOT + pos] = sr[i];
                    else {
                        int o = atomicAdd(ovcnt, 1);
                        if (o < OVCAP) ov[o] = make_int2(ds[i], sr[i]);
                    }
                }
            }
        }
    } else if (b < nfill + 128) {
        // ---- W -> bf16 transposed ----
        int wb = b - nfill;
        const float* W = (wb < 64) ? W1 : W2;
        unsigned short* o = (wb < 64) ? w1bf : w2bf;
        int idx = (wb & 63) * 256 + threadIdx.x;   // idx = k*128+n
        int kk = idx >> 7, n = idx & 127;
        o[n * 128 + kk] = f2bf(W[idx]);
    } else {
        // ---- x -> bf16 ----
        int i = (b - nfill - 128) * 256 + threadIdx.x;
        if (i < total4) {
            float4 v = *(const float4*)&x[(size_t)i * 4];
            ushort4v o;
            o.x = f2bf(v.x); o.y = f2bf(v.y); o.z = f2bf(v.z); o.w = f2bf(v.w);
            *(ushort4v*)&xb[(size_t)i * 4] = o;
        }
    }
}

// ---------------------------------------------------------------------------
// Gather-aggregate (R8-proven structure, drain widened 8->16). 32-lane group
// per node; slab candidates -> LDS compaction (ballot/popc, wave-sync) -> 16
// independent row gathers per batch. h = (1+eps)*x[n] + sum x[s], bf16 out.
// LDS 2KB -> occupancy stays high; VGPR ~70 -> ~28 waves/CU.
// ---------------------------------------------------------------------------
__global__ __launch_bounds__(256) void agg_slab_kernel(
        const unsigned short* __restrict__ xb,
        const int* __restrict__ counts,       // [NGRP][N]
        const int* __restrict__ slab,         // [NGRP][N][SSLOT]
        const int* __restrict__ ovcnt, const int2* __restrict__ ov,
        const float* __restrict__ epsp,
        unsigned short* __restrict__ hb,      // bf16 h out (may be null)
        float* __restrict__ hf,               // fp32 h out (used if hb null)
        int N) {
    __shared__ int comp[8][64];
    const int lane = threadIdx.x & 31;
    const int grpq = threadIdx.x >> 5;        // 0..7 node group in block
    const int base = threadIdx.x & 32;        // ballot shift for 32-lane group
    const int node = blockIdx.x * 8 + grpq;
    if (node >= N) return;
    const int c = lane * 4;
    const float epsv = 1.0f + epsp[0];

    // lane l covers seg g=l>>2, slots (l&3)*2, (l&3)*2+1
    int g = lane >> 2, s0 = (lane & 3) * 2;
    int2 sl = *(const int2*)&slab[((size_t)g * N + node) * SSLOT + s0];
    int cnt = min(counts[(size_t)g * N + node], SSLOT);
    bool v0 = s0 < cnt, v1 = (s0 + 1) < cnt;
    unsigned m0 = (unsigned)(__ballot(v0) >> base);
    unsigned m1 = (unsigned)(__ballot(v1) >> base);
    int t0 = __popc(m0);
    int total = t0 + __popc(m1);
    unsigned lt = (lane == 0) ? 0u : (~0u >> (32 - lane));
    if (v0) comp[grpq][__popc(m0 & lt)] = sl.x;
    if (v1) comp[grpq][t0 + __popc(m1 & lt)] = sl.y;
    // wave-synchronous LDS: same wave writes then reads its own slice

    ushort4v own = *(const ushort4v*)&xb[(size_t)node * DFEAT + c];
    float ax = epsv * bf2f(own.x), ay = epsv * bf2f(own.y);
    float az = epsv * bf2f(own.z), aw = epsv * bf2f(own.w);

    for (int i = 0; i < total; i += 16) {
        int4 q0 = *(const int4*)&comp[grpq][i];
        int4 q1 = *(const int4*)&comp[grpq][i + 4];
        int4 q2 = *(const int4*)&comp[grpq][i + 8];
        int4 q3 = *(const int4*)&comp[grpq][i + 12];
        int rem = total - i;
        int sj[16];
        sj[0]  = q0.x;
        sj[1]  = (rem > 1)  ? q0.y : q0.x;
        sj[2]  = (rem > 2)  ? q0.z : q0.x;
        sj[3]  = (rem > 3)  ? q0.w : q0.x;
        sj[4]  = (rem > 4)  ? q1.x : q0.x;
        sj[5]  = (rem > 5)  ? q1.y : q0.x;
        sj[6]  = (rem > 6)  ? q1.z : q0.x;
        sj[7]  = (rem > 7)  ? q1.w : q0.x;
        sj[8]  = (rem > 8)  ? q2.x : q0.x;
        sj[9]  = (rem > 9)  ? q2.y : q0.x;
        sj[10] = (rem > 10) ? q2.z : q0.x;
        sj[11] = (rem > 11) ? q2.w : q0.x;
        sj[12] = (rem > 12) ? q3.x : q0.x;
        sj[13] = (rem > 13) ? q3.y : q0.x;
        sj[14] = (rem > 14) ? q3.z : q0.x;
        sj[15] = (rem > 15) ? q3.w : q0.x;
        ushort4v u[16];
#pragma unroll
        for (int q = 0; q < 16; ++q)
            u[q] = *(const ushort4v*)&xb[(size_t)sj[q] * DFEAT + c];
#pragma unroll
        for (int q = 0; q < 16; ++q) {
            if (rem > q) {
                ax += bf2f(u[q].x); ay += bf2f(u[q].y);
                az += bf2f(u[q].z); aw += bf2f(u[q].w);
            }
        }
    }

    // overflow replay (tiny list, L2-resident)
    int ovn = min(ovcnt[0], OVCAP);
    int trips = (ovn + 31) >> 5;
    for (int t = 0; t < trips; ++t) {
        int j = t * 32 + lane;
        int2 e = (j < ovn) ? ov[j] : make_int2(-1, 0);
        unsigned long long b = __ballot(e.x == node);
        unsigned m = (unsigned)(b >> base);
        while (m) {
            int l = __ffs(m) - 1; m &= m - 1;
            int s = __shfl(e.y, base + l, 64);
            ushort4v u = *(const ushort4v*)&xb[(size_t)s * DFEAT + c];
            ax += bf2f(u.x); ay += bf2f(u.y);
            az += bf2f(u.z); aw += bf2f(u.w);
        }
    }

    if (hb) {
        ushort4v hv;
        hv.x = f2bf(ax); hv.y = f2bf(ay); hv.z = f2bf(az); hv.w = f2bf(aw);
        *(ushort4v*)&hb[(size_t)node * DFEAT + c] = hv;
    } else {
        *(float4*)&hf[(size_t)node * DFEAT + c] = make_float4(ax, ay, az, aw);
    }
}

// ---------------------------------------------------------------------------
// MFMA MLP (R4-proven): out = relu(h@W1+b1)@W2+b2, bf16 in / fp32 accum.
// ---------------------------------------------------------------------------
__global__ __launch_bounds__(256) void mlp_mfma_kernel(
        const unsigned short* __restrict__ hb,
        const float* __restrict__ hsrc,
        const unsigned short* __restrict__ w1bf,
        const unsigned short* __restrict__ w2bf,
        const float* __restrict__ b1, const float* __restrict__ b2,
        float* __restrict__ out, int N) {
    __shared__ unsigned short hlds[64 * 136];
    __shared__ unsigned short wlds[128 * 136];

    const int tid  = threadIdx.x;
    const int node0 = blockIdx.x * 64;
    const int lane = tid & 63;
    const int w    = tid >> 6;
    const int l15  = lane & 15;
    const int quad = lane >> 4;

    if (hb) {
        for (int i = tid; i < 64 * 16; i += 256) {
            int m = i >> 4, k0 = (i & 15) * 8;
            int node = node0 + m;
            short8v v = {0, 0, 0, 0, 0, 0, 0, 0};
            if (node < N) v = *(const short8v*)&hb[(size_t)node * DFEAT + k0];
            *(short8v*)&hlds[m * 136 + k0] = v;
        }
    } else {
        for (int i = tid; i < 64 * 32; i += 256) {
            int m = i >> 5, c = (i & 31) * 4;
            int node = node0 + m;
            float4 v = make_float4(0.f, 0.f, 0.f, 0.f);
            if (node < N) v = *(const float4*)&hsrc[(size_t)node * DFEAT + c];
            ushort4v o;
            o.x = f2bf(v.x); o.y = f2bf(v.y); o.z = f2bf(v.z); o.w = f2bf(v.w);
            *(ushort4v*)&hlds[m * 136 + c] = o;
        }
    }
    for (int i = tid; i < 128 * 16; i += 256) {
        int n = i >> 4, k0 = (i & 15) * 8;
        *(short8v*)&wlds[n * 136 + k0] = *(const short8v*)&w1bf[n * 128 + k0];
    }
    __syncthreads();

    const unsigned short* ha = &hlds[(w * 16 + l15) * 136 + quad * 8];

    for (int layer = 0; layer < 2; ++layer) {
        if (layer == 1) {
            __syncthreads();
            for (int i = tid; i < 128 * 16; i += 256) {
                int n = i >> 4, k0 = (i & 15) * 8;
                *(short8v*)&wlds[n * 136 + k0] = *(const short8v*)&w2bf[n * 128 + k0];
            }
            __syncthreads();
        }

        f32x4 acc[8];
#pragma unroll
        for (int nt = 0; nt < 8; ++nt) acc[nt] = (f32x4){0.f, 0.f, 0.f, 0.f};

#pragma unroll
        for (int s = 0; s < 4; ++s) {
            short8v a = *(const short8v*)&ha[s * 32];
#pragma unroll
            for (int nt = 0; nt < 8; ++nt) {
                short8v bf = *(const short8v*)&wlds[(nt * 16 + l15) * 136 + quad * 8 + s * 32];
                acc[nt] = __builtin_amdgcn_mfma_f32_16x16x32_bf16(a, bf, acc[nt], 0, 0, 0);
            }
        }

        const float* bias = layer ? b2 : b1;
        if (layer == 0) {
            __syncthreads();
#pragma unroll
            for (int nt = 0; nt < 8; ++nt) {
                float bv = bias[nt * 16 + l15];
#pragma unroll
                for (int r = 0; r < 4; ++r) {
                    float v = fmaxf(acc[nt][r] + bv, 0.f);
                    hlds[(w * 16 + quad * 4 + r) * 136 + nt * 16 + l15] = f2bf(v);
                }
            }
        } else {
#pragma unroll
            for (int nt = 0; nt < 8; ++nt) {
                float bv = bias[nt * 16 + l15];
#pragma unroll
                for (int r = 0; r < 4; ++r) {
                    int node = node0 + w * 16 + quad * 4 + r;
                    if (node < N)
                        out[(size_t)node * DFEAT + nt * 16 + l15] = acc[nt][r] + bv;
                }
            }
        }
    }
}

// ===========================================================================
// Fallback (tiny ws): atomic scatter + fp32 vector MLP
// ===========================================================================
__global__ void detect_idx_kernel(const int* __restrict__ ei, int* __restrict__ flag) {
    if (threadIdx.x == 0 && blockIdx.x == 0) {
        int orsum = 0;
#pragma unroll
        for (int i = 0; i < 128; ++i) orsum |= ei[2 * i + 1];
        flag[0] = (orsum == 0) ? 1 : 0;
    }
}

__global__ __launch_bounds__(256) void scatter_kernel(
        const float* __restrict__ x, const void* __restrict__ eiv,
        const int* __restrict__ flag, float* __restrict__ agg, int E) {
    unsigned gid = blockIdx.x * 256u + threadIdx.x;
    unsigned e = gid >> 5;
    if (e >= (unsigned)E) return;
    int c = (gid & 31u) * 4;
    int is64 = flag[0];
    int src = load_idx(eiv, is64, (size_t)e);
    int dst = load_idx(eiv, is64, (size_t)E + e);
    float4 v = *(const float4*)&x[(size_t)src * DFEAT + c];
    float* p = &agg[(size_t)dst * DFEAT + c];
    unsafeAtomicAdd(p + 0, v.x);
    unsafeAtomicAdd(p + 1, v.y);
    unsafeAtomicAdd(p + 2, v.z);
    unsafeAtomicAdd(p + 3, v.w);
}

__global__ __launch_bounds__(256) void mlp_kernel(
        const float* __restrict__ xp,
        const float* __restrict__ W1, const float* __restrict__ b1,
        const float* __restrict__ W2, const float* __restrict__ b2,
        const float* __restrict__ epsp, float* __restrict__ out) {
    __shared__ float hs[32][DFEAT];
    __shared__ float Wc[64][DFEAT];

    const int tid = threadIdx.x;
    const int node0 = blockIdx.x * 32;
    const float epsv = 1.0f + epsp[0];

    for (int i = tid; i < 32 * (DFEAT / 4); i += 256) {
        int n = i >> 5;
        int c = (i & 31) * 4;
        size_t off = (size_t)(node0 + n) * DFEAT + c;
        float4 h = *(const float4*)&out[off];
        float4 xv = *(const float4*)&xp[off];
        h.x += epsv * xv.x; h.y += epsv * xv.y;
        h.z += epsv * xv.z; h.w += epsv * xv.w;
        *(float4*)&hs[n][c] = h;
    }

    const int og = (tid & 31) * 4;
    const int ng = (tid >> 5) * 4;

    for (int layer = 0; layer < 2; ++layer) {
        const float* W = layer ? W2 : W1;
        const float* b = layer ? b2 : b1;

        float acc[4][4];
#pragma unroll
        for (int j = 0; j < 4; ++j) {
            float bj = b[og + j];
#pragma unroll
            for (int i = 0; i < 4; ++i) acc[i][j] = bj;
        }

        for (int chunk = 0; chunk < 2; ++chunk) {
            __syncthreads();
            for (int i = tid; i < 64 * (DFEAT / 4); i += 256) {
                int r = i >> 5;
                int c = (i & 31) * 4;
                *(float4*)&Wc[r][c] =
                    *(const float4*)&W[(size_t)(chunk * 64 + r) * DFEAT + c];
            }
            __syncthreads();
            const int kb = chunk * 64;
            for (int k = 0; k < 64; k += 4) {
                float4 h4[4], w4[4];
#pragma unroll
                for (int i = 0; i < 4; ++i)
                    h4[i] = *(const float4*)&hs[ng + i][kb + k];
#pragma unroll
                for (int j = 0; j < 4; ++j)
                    w4[j] = *(const float4*)&Wc[k + j][og];
#pragma unroll
                for (int i = 0; i < 4; ++i) {
                    acc[i][0] += h4[i].x * w4[0].x + h4[i].y * w4[1].x
                               + h4[i].z * w4[2].x + h4[i].w * w4[3].x;
                    acc[i][1] += h4[i].x * w4[0].y + h4[i].y * w4[1].y
                               + h4[i].z * w4[2].y + h4[i].w * w4[3].y;
                    acc[i][2] += h4[i].x * w4[0].z + h4[i].y * w4[1].z
                               + h4[i].z * w4[2].z + h4[i].w * w4[3].z;
                    acc[i][3] += h4[i].x * w4[0].w + h4[i].y * w4[1].w
                               + h4[i].z * w4[2].w + h4[i].w * w4[3].w;
                }
            }
        }
        __syncthreads();

        if (layer == 0) {
#pragma unroll
            for (int i = 0; i < 4; ++i) {
                float4 r;
                r.x = fmaxf(acc[i][0], 0.0f);
                r.y = fmaxf(acc[i][1], 0.0f);
                r.z = fmaxf(acc[i][2], 0.0f);
                r.w = fmaxf(acc[i][3], 0.0f);
                *(float4*)&hs[ng + i][og] = r;
            }
        } else {
#pragma unroll
            for (int i = 0; i < 4; ++i) {
                float4 r;
                r.x = acc[i][0]; r.y = acc[i][1];
                r.z = acc[i][2]; r.w = acc[i][3];
                *(float4*)&out[(size_t)(node0 + ng + i) * DFEAT + og] = r;
            }
        }
    }
}

extern "C" void kernel_launch(void* const* d_in, const int* in_sizes, int n_in,
                              void* d_out, int out_size, void* d_ws, size_t ws_size,
                              hipStream_t stream) {
    const float* x   = (const float*)d_in[0];
    const void*  ei  = d_in[1];
    const float* W1  = (const float*)d_in[2];
    const float* b1  = (const float*)d_in[3];
    const float* W2  = (const float*)d_in[4];
    const float* b2  = (const float*)d_in[5];
    const float* eps = (const float*)d_in[6];
    float* out = (float*)d_out;

    const int N = in_sizes[0] / DFEAT;      // 100000
    const int E = in_sizes[1] / 2;          // 1600000
    const int M = NGRP * N;                 // 800000 segments
    const int total4 = N * (DFEAT / 4);     // 3.2M float4s in x

    // ---- layout: [w1bf][w2bf][xb][counts][ovcnt][ov][slab][hb?] ----
    char* p = (char*)d_ws;
    unsigned short* w1bf = (unsigned short*)p;  p += 128 * 128 * 2;
    unsigned short* w2bf = (unsigned short*)p;  p += 128 * 128 * 2;
    unsigned short* xb = (unsigned short*)p;    p += (size_t)N * DFEAT * 2;
    int* counts = (int*)p;                      p += (size_t)M * 4;
    int* ovcnt = (int*)p;                       p += 64;
    int2* ov = (int2*)p;                        p += (size_t)OVCAP * 8;
    int* slab = (int*)p;                        p += (size_t)M * SSLOT * 4;
    size_t need_slim = (size_t)(p - (char*)d_ws);
    unsigned short* hb = (unsigned short*)p;    p += (size_t)N * DFEAT * 2;
    size_t need_full = (size_t)(p - (char*)d_ws);

    if (ws_size >= need_slim) {
        bool full = (ws_size >= need_full);
        int nfill = FILL_BLOCKS;
        if ((size_t)E > (size_t)FILL_BLOCKS * 256 * EPT)
            nfill = (E + 256 * EPT - 1) / (256 * EPT);
        int xbBlocks = (total4 + 255) / 256;

        hipMemsetAsync(counts, 0, (size_t)M * 4 + 64, stream);  // counts+ovcnt
        prep_kernel<<<nfill + 128 + xbBlocks, 256, 0, stream>>>(
            W1, W2, w1bf, w2bf, x, xb, total4, ei,
            counts, ovcnt, ov, slab, E, N, nfill);
        agg_slab_kernel<<<(N + 7) / 8, 256, 0, stream>>>(
            xb, counts, slab, ovcnt, ov, eps,
            full ? hb : nullptr, out, N);
        mlp_mfma_kernel<<<(N + 63) / 64, 256, 0, stream>>>(
            full ? hb : nullptr, out, w1bf, w2bf, b1, b2, out, N);
        return;
    }

    // ---- fallback: atomic scatter + fp32 MLP ----
    int* flag3 = (int*)d_ws;
    detect_idx_kernel<<<1, 64, 0, stream>>>((const int*)ei, flag3);
    hipMemsetAsync(d_out, 0, (size_t)out_size * sizeof(float), stream);
    unsigned total = (unsigned)E * 32u;
    scatter_kernel<<<(total + 255u) / 256u, 256, 0, stream>>>(x, ei, flag3, out, E);
    mlp_kernel<<<N / 32, 256, 0, stream>>>(x, W1, b1, W2, b2, eps, out);
}